// Round 1
// baseline (2023.790 us; speedup 1.0000x reference)
//
#include <hip/hip_runtime.h>
#include <hip/hip_bf16.h>
#include <math.h>

#define HEADS  4
#define HALF   256
#define N_KEYS 512
#define KNN    32
#define V_DIM  1024
#define IN_DIM 1024

// ---------------------------------------------------------------------------
// Tiled fp32 GEMM: C[m,n] = sum_k A[m,k] * B[k,n]
//   BT=false: B is K x N row-major (normal)
//   BT=true : B is N x K row-major (we dot rows of B)
// 128x128 tile, 256 threads, 8x8 microtile, KT=8.
// ---------------------------------------------------------------------------
template<bool BT>
__global__ __launch_bounds__(256) void gemm_k(
    const float* __restrict__ A, int lda, long aBatch,
    const float* __restrict__ B, int ldb, long bBatch,
    float* __restrict__ C, int ldc, long cBatch,
    int K)
{
    const int z = blockIdx.z;
    A += (long)z * aBatch;
    B += (long)z * bBatch;
    C += (long)z * cBatch;

    __shared__ float As[8][128];
    __shared__ float Bs[8][128];

    const int t  = threadIdx.x;
    const int tx = t & 15, ty = t >> 4;
    const int m0 = blockIdx.y * 128, n0 = blockIdx.x * 128;

    // staging indices
    const int arow = t >> 1;        // 0..127
    const int akc  = (t & 1) * 4;   // 0 or 4
    const int brow = t >> 5;        // 0..7   (NN path)
    const int bcol = (t & 31) * 4;  // 0..124 (NN path)

    const float* Aptr = A + (size_t)(m0 + arow) * lda + akc;
    const float* Bptr = BT ? (B + (size_t)(n0 + arow) * ldb + akc)
                           : (B + (size_t)brow * ldb + n0 + bcol);

    float acc[8][8] = {{0.f}};

    for (int k0 = 0; k0 < K; k0 += 8) {
        float4 av = *(const float4*)(Aptr + k0);
        As[akc+0][arow] = av.x;
        As[akc+1][arow] = av.y;
        As[akc+2][arow] = av.z;
        As[akc+3][arow] = av.w;
        if (BT) {
            float4 bv = *(const float4*)(Bptr + k0);
            Bs[akc+0][arow] = bv.x;
            Bs[akc+1][arow] = bv.y;
            Bs[akc+2][arow] = bv.z;
            Bs[akc+3][arow] = bv.w;
        } else {
            float4 bv = *(const float4*)(Bptr + (size_t)k0 * ldb);
            *(float4*)&Bs[brow][bcol] = bv;
        }
        __syncthreads();
        #pragma unroll
        for (int kk = 0; kk < 8; ++kk) {
            float4 al = *(const float4*)&As[kk][ty*4];
            float4 ah = *(const float4*)&As[kk][ty*4+64];
            float4 bl = *(const float4*)&Bs[kk][tx*4];
            float4 bh = *(const float4*)&Bs[kk][tx*4+64];
            float a8[8] = {al.x,al.y,al.z,al.w,ah.x,ah.y,ah.z,ah.w};
            float b8[8] = {bl.x,bl.y,bl.z,bl.w,bh.x,bh.y,bh.z,bh.w};
            #pragma unroll
            for (int i = 0; i < 8; ++i)
                #pragma unroll
                for (int j = 0; j < 8; ++j)
                    acc[i][j] += a8[i] * b8[j];
        }
        __syncthreads();
    }

    #pragma unroll
    for (int i = 0; i < 8; ++i) {
        int m = m0 + ((i < 4) ? (ty*4 + i) : (64 + ty*4 + i - 4));
        float4 lo = {acc[i][0], acc[i][1], acc[i][2], acc[i][3]};
        float4 hi = {acc[i][4], acc[i][5], acc[i][6], acc[i][7]};
        *(float4*)(C + (size_t)m * ldc + n0 + tx*4)      = lo;
        *(float4*)(C + (size_t)m * ldc + n0 + 64 + tx*4) = hi;
    }
}

// ---------------------------------------------------------------------------
// Top-k: one wave (64 threads) per (b,h).
// scores layout: ((b*4+h)*2 + s)*512 + n
// Sequential argmax selection => descending order, ties -> lower index,
// exactly matching lax.top_k semantics.
// ---------------------------------------------------------------------------
__device__ __forceinline__ void wave_argmax(float& best, int& bi) {
    #pragma unroll
    for (int off = 32; off; off >>= 1) {
        float ov = __shfl_xor(best, off);
        int   oi = __shfl_xor(bi, off);
        if (ov > best || (ov == best && oi < bi)) { best = ov; bi = oi; }
    }
}

__global__ __launch_bounds__(64) void topk_kernel(
    const float* __restrict__ scores,
    int* __restrict__ idx_out, float* __restrict__ w_out)
{
    const int bh   = blockIdx.x;      // b*4 + h
    const int lane = threadIdx.x;
    const float* sc0 = scores + (size_t)bh * 1024;
    const float* sc1 = sc0 + 512;

    __shared__ float s1v[32], s2v[32], bsv[32];
    __shared__ int   i1v[32], i2v[32], bfv[32];

    float v[8], u[8];
    #pragma unroll
    for (int j = 0; j < 8; ++j) {
        v[j] = sc0[j*64 + lane];
        u[j] = sc1[j*64 + lane];
    }

    const float NEGINF = -__builtin_inff();

    // top-32 of sub-key 0
    for (int i = 0; i < 32; ++i) {
        float best = NEGINF; int bi = 1 << 30;
        #pragma unroll
        for (int j = 0; j < 8; ++j) {
            int n = j*64 + lane;
            if (v[j] > best) { best = v[j]; bi = n; }
        }
        wave_argmax(best, bi);
        if (lane == 0) { s1v[i] = best; i1v[i] = bi; }
        #pragma unroll
        for (int j = 0; j < 8; ++j)
            if (j*64 + lane == bi) v[j] = NEGINF;
    }
    // top-32 of sub-key 1
    for (int i = 0; i < 32; ++i) {
        float best = NEGINF; int bi = 1 << 30;
        #pragma unroll
        for (int j = 0; j < 8; ++j) {
            int n = j*64 + lane;
            if (u[j] > best) { best = u[j]; bi = n; }
        }
        wave_argmax(best, bi);
        if (lane == 0) { s2v[i] = best; i2v[i] = bi; }
        #pragma unroll
        for (int j = 0; j < 8; ++j)
            if (j*64 + lane == bi) u[j] = NEGINF;
    }
    __syncthreads();

    // cartesian 32x32 = 1024 candidates; 16 per lane
    float c[16];
    #pragma unroll
    for (int j = 0; j < 16; ++j) {
        int f = j*64 + lane;
        c[j] = s1v[f >> 5] + s2v[f & 31];
    }

    float m0 = 0.f, ssum = 0.f;
    for (int i = 0; i < 32; ++i) {
        float best = NEGINF; int bf = 1 << 30;
        #pragma unroll
        for (int j = 0; j < 16; ++j) {
            int f = j*64 + lane;
            if (c[j] > best) { best = c[j]; bf = f; }
        }
        wave_argmax(best, bf);
        if (i == 0) m0 = best;            // first selected == max
        ssum += expf(best - m0);          // uniform across lanes
        if (lane == 0) { bsv[i] = best; bfv[i] = bf; }
        #pragma unroll
        for (int j = 0; j < 16; ++j)
            if (j*64 + lane == bf) c[j] = NEGINF;
    }
    __syncthreads();

    if (lane < 32) {
        int f   = bfv[lane];
        float w = expf(bsv[lane] - m0) / ssum;
        int id  = i1v[f >> 5] * N_KEYS + i2v[f & 31];
        idx_out[(size_t)bh * KNN + lane] = id;
        w_out  [(size_t)bh * KNN + lane] = w;
    }
}

// ---------------------------------------------------------------------------
// Gather + weighted embedding-bag sum.
// One block per batch row; 256 threads x float4 covers V_DIM=1024.
// out[b, :] = sum over 128 (h,k) pairs of w * values[idx]
// ---------------------------------------------------------------------------
__global__ __launch_bounds__(256) void gather_kernel(
    const float* __restrict__ values,
    const int*   __restrict__ idx,
    const float* __restrict__ w,
    float*       __restrict__ out)
{
    const int b = blockIdx.x;
    const int t = threadIdx.x;
    __shared__ float ws[HEADS * KNN];
    __shared__ int   is[HEADS * KNN];
    if (t < HEADS * KNN) {
        ws[t] = w  [(size_t)b * HEADS * KNN + t];
        is[t] = idx[(size_t)b * HEADS * KNN + t];
    }
    __syncthreads();

    float4 acc = {0.f, 0.f, 0.f, 0.f};
    #pragma unroll 4
    for (int k = 0; k < HEADS * KNN; ++k) {
        const float4* row = (const float4*)(values + (size_t)is[k] * V_DIM);
        float4 vv = row[t];
        float  wk = ws[k];
        acc.x += wk * vv.x;
        acc.y += wk * vv.y;
        acc.z += wk * vv.z;
        acc.w += wk * vv.w;
    }
    ((float4*)out)[(size_t)b * (V_DIM/4) + t] = acc;
}

// ---------------------------------------------------------------------------
extern "C" void kernel_launch(void* const* d_in, const int* in_sizes, int n_in,
                              void* d_out, int out_size, void* d_ws, size_t ws_size,
                              hipStream_t stream)
{
    const float* x      = (const float*)d_in[0];  // (bs, 1024)
    const float* wq     = (const float*)d_in[1];  // (1024, 2048)
    const float* keys   = (const float*)d_in[2];  // (4, 2, 512, 256)
    const float* values = (const float*)d_in[3];  // (262144, 1024)
    float* out = (float*)d_out;

    const int bs = in_sizes[0] / IN_DIM;          // 4096

    // workspace layout (fp32 elements)
    float* q      = (float*)d_ws;                          // bs x 2048
    float* scores = q + (size_t)bs * 2048;                 // bs x 8 x 512
    int*   idxb   = (int*)(scores + (size_t)bs * 4096);    // bs x 4 x 32
    float* wb     = (float*)(idxb + (size_t)bs * HEADS * KNN);

    dim3 blk(256);

    // q = x @ w_query   (M=bs, N=2048, K=1024), NN
    gemm_k<false><<<dim3(2048/128, bs/128, 1), blk, 0, stream>>>(
        x, IN_DIM, 0,
        wq, 2048, 0,
        q, 2048, 0,
        IN_DIM);

    // scores[z]: (M=bs, N=512, K=256), NT, batched over z = h*2+s (8)
    gemm_k<true><<<dim3(N_KEYS/128, bs/128, 8), blk, 0, stream>>>(
        q, 2048, 256,
        keys, HALF, (long)N_KEYS * HALF,
        scores, 4096, N_KEYS,
        HALF);

    // per-(b,h) top-k + softmax
    topk_kernel<<<bs * HEADS, 64, 0, stream>>>(scores, idxb, wb);

    // gather + weighted sum
    gather_kernel<<<bs, 256, 0, stream>>>(values, idxb, wb, out);
}